// Round 7
// baseline (114.855 us; speedup 1.0000x reference)
//
#include <hip/hip_runtime.h>
#include <math.h>

#define NB 1024   // batch
#define NC 64     // input dim
#define NH 128    // hidden dim
#define MAX_IT 500
#define TOLF 1e-3f

#define PSTR 65   // uint2 stride of P/Z arrays (130 dwords)
#define TSTR 66   // dword stride of T arrays

typedef _Float16 h2 __attribute__((ext_vector_type(2)));

#if __has_builtin(__builtin_amdgcn_fdot2)
#define FDOT2(a, b, c) __builtin_amdgcn_fdot2((a), (b), (c), false)
#else
#define FDOT2(a, b, c) fmaf((float)(a).x, (float)(b).x, fmaf((float)(a).y, (float)(b).y, (c)))
#endif

#if __has_builtin(__builtin_amdgcn_wave_barrier)
#define WAVE_FENCE() __builtin_amdgcn_wave_barrier()
#else
#define WAVE_FENCE()
#endif

__device__ __forceinline__ unsigned pack_h2(float a, float b) {
    union { h2 h; unsigned u; } cv;
    cv.h.x = (_Float16)a; cv.h.y = (_Float16)b; return cv.u;
}
__device__ __forceinline__ h2 as_h2(unsigned u) {
    union { unsigned u; h2 h; } cv; cv.u = u; return cv.h;
}
__device__ __forceinline__ float rcp_fast(float x) {
#if __has_builtin(__builtin_amdgcn_rcpf)
    return __builtin_amdgcn_rcpf(x);
#else
    return 1.0f / x;
#endif
}
// sigmoid + softplus sharing one exp
__device__ __forceinline__ void sigsp(float a, float& sig, float& sp) {
    const float e = __expf(-fabsf(a));
    const float r = rcp_fast(1.0f + e);
    sig = (a >= 0.0f) ? r : e * r;
    sp  = fmaxf(a, 0.0f) + __logf(1.0f + e);
}

#define REP64(M) \
  M(0)  M(1)  M(2)  M(3)  M(4)  M(5)  M(6)  M(7)  \
  M(8)  M(9)  M(10) M(11) M(12) M(13) M(14) M(15) \
  M(16) M(17) M(18) M(19) M(20) M(21) M(22) M(23) \
  M(24) M(25) M(26) M(27) M(28) M(29) M(30) M(31) \
  M(32) M(33) M(34) M(35) M(36) M(37) M(38) M(39) \
  M(40) M(41) M(42) M(43) M(44) M(45) M(46) M(47) \
  M(48) M(49) M(50) M(51) M(52) M(53) M(54) M(55) \
  M(56) M(57) M(58) M(59) M(60) M(61) M(62) M(63)

// One wave = one sample (lane c owns component c). Loop is LDS-weight-BW-bound
// (512 KB/CU/iter ~ 4300 cyc/iter, confirmed R3-R6). Fix: pin the Wz1 slice
// (fwd rows l,l+64 + adj cols l,l+64 = 256 dwords/lane) in VGPRs. R5 (array)
// and R6 (named vars) both failed: compiler rematerializes LDS loads into the
// loop (VGPR_Count stayed 164). R7 forces liveness with empty asm "+v" pins —
// the value becomes opaque, rematerialization is illegal.
__launch_bounds__(256, 1)
__global__ void blnn_kernel(const float* __restrict__ xin,
                            const float* __restrict__ Wy0,
                            const float* __restrict__ by0,
                            const float* __restrict__ Wy1,
                            const float* __restrict__ by1,
                            const float* __restrict__ Wz1,
                            const float* __restrict__ Wy2,
                            const float* __restrict__ by2,
                            const float* __restrict__ Wz2,
                            float* __restrict__ out)
{
    __shared__ __align__(16) unsigned P0i[32 * 2 * PSTR];  // Wy0 fwd: [pk][slot]
    __shared__ __align__(16) unsigned P1i[32 * 2 * PSTR];  // Wy1 fwd
    __shared__ __align__(16) unsigned PZi[64 * 2 * PSTR];  // Wz1 fwd bounce (clipped)
    __shared__ __align__(16) unsigned TZi[64 * 2 * PSTR];  // Wz1 adj bounce
    __shared__ __align__(16) unsigned T0j[64 * TSTR];      // Wy0 adj: [c][pj]
    __shared__ __align__(16) unsigned T1j[64 * TSTR];      // Wy1 adj
    __shared__ __align__(16) _Float16 xh [4][64];
    __shared__ __align__(16) _Float16 h0h[4][128];
    __shared__ __align__(16) _Float16 v1h[4][128];
    __shared__ __align__(16) _Float16 v0h[4][128];

    const int tid = threadIdx.x;
    const int s   = tid >> 6;
    const int l   = tid & 63;
    const int sample = blockIdx.x * 4 + s;

    // ---- stage weights: fp32 global -> packed fp16 LDS ----
    const float2* Wy0f2 = (const float2*)Wy0;   // [128][32] float2
    const float2* Wy1f2 = (const float2*)Wy1;
    const float2* Wz1f2 = (const float2*)Wz1;   // [128][64] float2
    for (int idx = tid; idx < 128 * 32; idx += 256) {        // P0/P1 fwd
        const int pk = idx & 31, r = idx >> 5;
        const int slot = ((r & 63) << 1) | (r >> 6);
        const float2 a = Wy0f2[idx], b = Wy1f2[idx];
        P0i[pk * 2 * PSTR + slot] = pack_h2(a.x, a.y);
        P1i[pk * 2 * PSTR + slot] = pack_h2(b.x, b.y);
    }
    for (int idx = tid; idx < 128 * 64; idx += 256) {        // PZ fwd (clip >= 0)
        const int pk = idx & 63, r = idx >> 6;
        const int slot = ((r & 63) << 1) | (r >> 6);
        const float2 a = Wz1f2[idx];
        PZi[pk * 2 * PSTR + slot] = pack_h2(fmaxf(a.x, 0.0f), fmaxf(a.y, 0.0f));
    }
    for (int idx = tid; idx < 64 * 128; idx += 256) {        // TZ adj (clip >= 0)
        const int c = idx & 127, pj = idx >> 7;
        const int slot = ((c & 63) << 1) | (c >> 6);
        TZi[pj * 2 * PSTR + slot] = pack_h2(fmaxf(Wz1[(2 * pj) * 128 + c], 0.0f),
                                            fmaxf(Wz1[(2 * pj + 1) * 128 + c], 0.0f));
    }
    for (int idx = tid; idx < 64 * 64; idx += 256) {         // T0/T1 adj [c][pj]
        const int c = idx & 63, pj = idx >> 6;
        T0j[c * TSTR + pj] = pack_h2(Wy0[(2 * pj) * 64 + c], Wy0[(2 * pj + 1) * 64 + c]);
        T1j[c * TSTR + pj] = pack_h2(Wy1[(2 * pj) * 64 + c], Wy1[(2 * pj + 1) * 64 + c]);
    }

    // per-lane constants
    const float wy2  = Wy2[l];
    const float wz2a = fmaxf(Wz2[l], 0.0f);
    const float wz2b = fmaxf(Wz2[l + 64], 0.0f);
    const float b0a = by0[l], b0b = by0[l + 64];
    const float b1a = by1[l], b1b = by1[l + 64];
    const float b2  = by2[0];
    const float z   = xin[sample * NC + l];

    __syncthreads();   // staging done — the ONLY block-wide barrier

    // ---- pin Wz1 in VGPRs: fwd rows (l,l+64) + adj cols (l,l+64) ----
    // asm "+v" makes each value opaque: the compiler CANNOT rematerialize the
    // LDS load inside the loop (R5/R6 failure mode) and must keep it live.
    const uint2* WZ = (const uint2*)PZi;   // uint2 idx = pj*PSTR + l
    const uint2* AZ = (const uint2*)TZi;
#define DECL_WZ(i) \
    unsigned wzfx##i, wzfy##i, wzax##i, wzay##i; \
    { uint2 tf = WZ[(i) * PSTR + l]; uint2 ta = AZ[(i) * PSTR + l]; \
      wzfx##i = tf.x; wzfy##i = tf.y; wzax##i = ta.x; wzay##i = ta.y; } \
    asm volatile("" : "+v"(wzfx##i), "+v"(wzfy##i), "+v"(wzax##i), "+v"(wzay##i));
    REP64(DECL_WZ)
#undef DECL_WZ

    const h2* xh2  = (const h2*)&xh [s][0];
    const h2* h0h2 = (const h2*)&h0h[s][0];
    const h2* v1h2 = (const h2*)&v1h[s][0];
    const h2* v0h2 = (const h2*)&v0h[s][0];
    const uint2* W0 = (const uint2*)P0i;   // uint2 idx = pk*PSTR + l
    const uint2* W1 = (const uint2*)P1i;
    const uint2* T0q = (const uint2*)T0j;  // uint2 idx = c*(TSTR/2) + pjp
    const uint2* T1q = (const uint2*)T1j;

    float x1 = z;            // start at z
    float lam = 1.0f, prev_n = 3.4e38f;

    for (int it = 0; it < MAX_IT; ++it) {
        xh[s][l] = (_Float16)x1;
        WAVE_FENCE();

        // ---- layer 0 forward: a = Wy0 x + by0 (rows l, l+64) ----
        float c00 = b0a, c01 = 0.f, c10 = b0b, c11 = 0.f;
        #pragma unroll
        for (int pk = 0; pk < 32; pk += 2) {
            const h2 xa = xh2[pk], xb = xh2[pk + 1];
            const uint2 wA = W0[pk * PSTR + l];
            const uint2 wB = W0[(pk + 1) * PSTR + l];
            c00 = FDOT2(as_h2(wA.x), xa, c00);
            c10 = FDOT2(as_h2(wA.y), xa, c10);
            c01 = FDOT2(as_h2(wB.x), xb, c01);
            c11 = FDOT2(as_h2(wB.y), xb, c11);
        }
        float sig0a, sp0a, sig0b, sp0b;
        sigsp(c00 + c01, sig0a, sp0a);
        sigsp(c10 + c11, sig0b, sp0b);
        h0h[s][l]      = (_Float16)sp0a;
        h0h[s][l + 64] = (_Float16)sp0b;
        WAVE_FENCE();

        // ---- layer 1 forward: a = Wz1+ h0 + Wy1 x + by1 (Wz1 from REGS) ----
        c00 = b1a; c01 = 0.f; c10 = b1b; c11 = 0.f;
#define L1_STEP(i) { const h2 hv = h0h2[i]; \
        if ((i) & 1) { c01 = FDOT2(as_h2(wzfx##i), hv, c01); \
                       c11 = FDOT2(as_h2(wzfy##i), hv, c11); } \
        else         { c00 = FDOT2(as_h2(wzfx##i), hv, c00); \
                       c10 = FDOT2(as_h2(wzfy##i), hv, c10); } }
        REP64(L1_STEP)
#undef L1_STEP
        #pragma unroll
        for (int pk = 0; pk < 32; pk += 2) {
            const h2 xa = xh2[pk], xb = xh2[pk + 1];
            const uint2 wA = W1[pk * PSTR + l];
            const uint2 wB = W1[(pk + 1) * PSTR + l];
            c00 = FDOT2(as_h2(wA.x), xa, c00);
            c10 = FDOT2(as_h2(wA.y), xa, c10);
            c01 = FDOT2(as_h2(wB.x), xb, c01);
            c11 = FDOT2(as_h2(wB.y), xb, c11);
        }
        float sig1a, h1a, sig1b, h1b;
        sigsp(c00 + c01, sig1a, h1a);
        sigsp(c10 + c11, sig1b, h1b);
        // scalar head: p = Wz2.h1 + Wy2.x + by2 (wave butterfly)
        float p = wz2a * h1a + wz2b * h1b + wy2 * x1;
        #pragma unroll
        for (int off = 32; off > 0; off >>= 1) p += __shfl_xor(p, off, 64);
        const float e2 = __expf(-fabsf(p + b2));
        const float r2 = rcp_fast(1.0f + e2);
        const float sig2 = ((p + b2) >= 0.0f) ? r2 : e2 * r2;
        v1h[s][l]      = (_Float16)(sig2 * sig1a * wz2a);
        v1h[s][l + 64] = (_Float16)(sig2 * sig1b * wz2b);
        WAVE_FENCE();

        // ---- adjoint: v0 = sig0 * (Wz1+^T v1)  (Wz1^T from REGS) ----
        float t00 = 0.f, t01 = 0.f, t10 = 0.f, t11 = 0.f;
#define ADJ_STEP(i) { const h2 vv = v1h2[i]; \
        if ((i) & 1) { t01 = FDOT2(as_h2(wzax##i), vv, t01); \
                       t11 = FDOT2(as_h2(wzay##i), vv, t11); } \
        else         { t00 = FDOT2(as_h2(wzax##i), vv, t00); \
                       t10 = FDOT2(as_h2(wzay##i), vv, t10); } }
        REP64(ADJ_STEP)
#undef ADJ_STEP
        v0h[s][l]      = (_Float16)(sig0a * (t00 + t01));
        v0h[s][l + 64] = (_Float16)(sig0b * (t10 + t11));
        WAVE_FENCE();

        // ---- g = x + sig2*Wy2^T + Wy1^T v1 + Wy0^T v0 (b64 T reads) ----
        float g0 = fmaf(sig2, wy2, x1), g1 = 0.f, g2 = 0.f, g3 = 0.f;
        #pragma unroll
        for (int pjp = 0; pjp < 32; ++pjp) {
            const uint2 w1 = T1q[l * (TSTR / 2) + pjp];
            g0 = FDOT2(as_h2(w1.x), v1h2[2 * pjp],     g0);
            g1 = FDOT2(as_h2(w1.y), v1h2[2 * pjp + 1], g1);
        }
        #pragma unroll
        for (int pjp = 0; pjp < 32; ++pjp) {
            const uint2 w0 = T0q[l * (TSTR / 2) + pjp];
            g2 = FDOT2(as_h2(w0.x), v0h2[2 * pjp],     g2);
            g3 = FDOT2(as_h2(w0.y), v0h2[2 * pjp + 1], g3);
        }
        const float g = (g0 + g1) + (g2 + g3);

        // ---- adaptive Richardson update (exact R3 solver) ----
        const float resid = z - g;
        float n2 = resid * resid;
        #pragma unroll
        for (int off = 32; off > 0; off >>= 1) n2 += __shfl_xor(n2, off, 64);
        const float n = sqrtf(n2);
        if (n < TOLF) break;                       // this wave is done
        if (n > prev_n * 0.999f) lam *= 0.5f;      // adaptive Richardson
        const float step = fmaxf(lam, 1.0f / (float)(it + 2));
        x1 = fmaf(step, resid, x1);
        prev_n = n;
    }

    out[sample * NC + l] = x1 + z;   // + CONVEX * z
}

extern "C" void kernel_launch(void* const* d_in, const int* in_sizes, int n_in,
                              void* d_out, int out_size, void* d_ws, size_t ws_size,
                              hipStream_t stream) {
    const float* xin = (const float*)d_in[0];
    const float* Wy0 = (const float*)d_in[1];
    const float* by0 = (const float*)d_in[2];
    const float* Wy1 = (const float*)d_in[3];
    const float* by1 = (const float*)d_in[4];
    const float* Wz1 = (const float*)d_in[5];
    const float* Wy2 = (const float*)d_in[6];
    const float* by2 = (const float*)d_in[7];
    const float* Wz2 = (const float*)d_in[8];
    float* out = (float*)d_out;

    blnn_kernel<<<dim3(NB / 4), dim3(256), 0, stream>>>(
        xin, Wy0, by0, Wy1, by1, Wz1, Wy2, by2, Wz2, out);
}

// Round 8
// 101.216 us; speedup vs baseline: 1.1347x; 1.1347x over previous
//
#include <hip/hip_runtime.h>
#include <math.h>

#define NB 1024   // batch
#define NC 64     // input dim
#define NH 128    // hidden dim
#define MAX_IT 500
#define TOLF 1e-3f

typedef _Float16 h2 __attribute__((ext_vector_type(2)));

#if __has_builtin(__builtin_amdgcn_fdot2)
#define FDOT2(a, b, c) __builtin_amdgcn_fdot2((a), (b), (c), false)
#else
#define FDOT2(a, b, c) fmaf((float)(a).x, (float)(b).x, fmaf((float)(a).y, (float)(b).y, (c)))
#endif

__device__ __forceinline__ unsigned pack_h2(float a, float b) {
    union { h2 h; unsigned u; } cv;
    cv.h.x = (_Float16)a; cv.h.y = (_Float16)b; return cv.u;
}
__device__ __forceinline__ h2 as_h2(unsigned u) {
    union { unsigned u; h2 h; } cv; cv.u = u; return cv.h;
}
__device__ __forceinline__ float rcp_fast(float x) {
#if __has_builtin(__builtin_amdgcn_rcpf)
    return __builtin_amdgcn_rcpf(x);
#else
    return 1.0f / x;
#endif
}
// sigmoid + softplus sharing one exp
__device__ __forceinline__ void sigsp(float a, float& sig, float& sp) {
    const float e = __expf(-fabsf(a));
    const float r = rcp_fast(1.0f + e);
    sig = (a >= 0.0f) ? r : e * r;
    sp  = fmaxf(a, 0.0f) + __logf(1.0f + e);
}

// R8: weight stream shared across the block's 4 samples (R3-R7 proved the old
// one-wave-one-sample structure is pinned at 512 KB LDS/CU/iter; this cuts
// unique weight bytes to 128 KB/CU/iter).
//   Row phases (h0, h1/v1, v0): wave w owns rows r = w*32+(l&31); lanes l and
//     l+32 broadcast one weight stream; each lane evaluates 2 samples
//     (u = l>>5 -> samples u, u+2), so one weight read feeds 4 sample-chains.
//   Col phase (g/resid/x-update): lane owns (c = w*16+(l&15), sample e=l>>4);
//     weight column read broadcast by the 4 lanes sharing c.
// Activations flow through LDS (fp16, b128 reads); 6 __syncthreads per iter.
// Solver: exact R3 adaptive Richardson; lockstep over 4 samples per block.
__launch_bounds__(256, 1)
__global__ void blnn_kernel(const float* __restrict__ xin,
                            const float* __restrict__ Wy0,
                            const float* __restrict__ by0,
                            const float* __restrict__ Wy1,
                            const float* __restrict__ by1,
                            const float* __restrict__ Wz1,
                            const float* __restrict__ Wy2,
                            const float* __restrict__ by2,
                            const float* __restrict__ Wz2,
                            float* __restrict__ out)
{
    // forward row-major (pairs along k): uint2 = 4 consecutive k of one row
    __shared__ __align__(16) unsigned F0s[128 * 34];  // Wy0 [r][pkp] stride 17 u2
    __shared__ __align__(16) unsigned F1s[128 * 34];  // Wy1
    __shared__ __align__(16) unsigned FZs[128 * 66];  // clip(Wz1) [r][pjp] stride 33 u2
    // adjoint col-major (pairs along reduced dim j)
    __shared__ __align__(16) unsigned AZs[128 * 66];  // clip(Wz1)^T [c][pjp] stride 33
    __shared__ __align__(16) unsigned T1s[64 * 66];   // Wy1^T [c][pjp]
    __shared__ __align__(16) unsigned T0s[64 * 66];   // Wy0^T
    __shared__ __align__(16) _Float16 xh [4][64];
    __shared__ __align__(16) _Float16 h0h[4][128];
    __shared__ __align__(16) _Float16 v1h[4][128];
    __shared__ __align__(16) _Float16 v0h[4][128];
    __shared__ float hp[4][4];    // head partials [wave][sample]
    __shared__ float npar[4][4];  // norm^2 partials [wave][sample]
    __shared__ unsigned wyq[32];  // Wy2 pairs

    const int tid = threadIdx.x;
    const int w = tid >> 6;
    const int l = tid & 63;

    uint2* F0q = (uint2*)F0s;
    uint2* F1q = (uint2*)F1s;
    uint2* FZq = (uint2*)FZs;
    uint2* AZq = (uint2*)AZs;
    uint2* T1q = (uint2*)T1s;
    uint2* T0q = (uint2*)T0s;

    // ---- staging: fp32 global -> packed fp16 LDS ----
    const float4* Wy0f4 = (const float4*)Wy0;   // [128][16] float4
    const float4* Wy1f4 = (const float4*)Wy1;
    const float4* Wz1f4 = (const float4*)Wz1;   // [128][32] float4
    for (int idx = tid; idx < 128 * 16; idx += 256) {
        const int r = idx >> 4, p = idx & 15;
        const float4 a = Wy0f4[idx];
        F0q[r * 17 + p] = make_uint2(pack_h2(a.x, a.y), pack_h2(a.z, a.w));
        const float4 b = Wy1f4[idx];
        F1q[r * 17 + p] = make_uint2(pack_h2(b.x, b.y), pack_h2(b.z, b.w));
    }
    for (int idx = tid; idx < 128 * 32; idx += 256) {
        const int r = idx >> 5, p = idx & 31;
        const float4 a = Wz1f4[idx];
        FZq[r * 33 + p] = make_uint2(pack_h2(fmaxf(a.x, 0.f), fmaxf(a.y, 0.f)),
                                     pack_h2(fmaxf(a.z, 0.f), fmaxf(a.w, 0.f)));
    }
    for (int idx = tid; idx < 128 * 32; idx += 256) {
        const int c = idx & 127, p = idx >> 7;
        AZq[c * 33 + p] = make_uint2(
            pack_h2(fmaxf(Wz1[(4 * p + 0) * 128 + c], 0.f), fmaxf(Wz1[(4 * p + 1) * 128 + c], 0.f)),
            pack_h2(fmaxf(Wz1[(4 * p + 2) * 128 + c], 0.f), fmaxf(Wz1[(4 * p + 3) * 128 + c], 0.f)));
    }
    for (int idx = tid; idx < 64 * 32; idx += 256) {
        const int c = idx & 63, p = idx >> 6;
        T1q[c * 33 + p] = make_uint2(pack_h2(Wy1[(4 * p + 0) * 64 + c], Wy1[(4 * p + 1) * 64 + c]),
                                     pack_h2(Wy1[(4 * p + 2) * 64 + c], Wy1[(4 * p + 3) * 64 + c]));
        T0q[c * 33 + p] = make_uint2(pack_h2(Wy0[(4 * p + 0) * 64 + c], Wy0[(4 * p + 1) * 64 + c]),
                                     pack_h2(Wy0[(4 * p + 2) * 64 + c], Wy0[(4 * p + 3) * 64 + c]));
    }
    if (tid < 32) wyq[tid] = pack_h2(Wy2[2 * tid], Wy2[2 * tid + 1]);
    xh[w][l] = (_Float16)xin[(blockIdx.x * 4 + w) * 64 + l];   // x0 = z

    // ---- row-role constants (rows rl; samples u, u+2) ----
    const int rl = (w << 5) + (l & 31);
    const int u  = l >> 5;
    const float b0r  = by0[rl], b1r = by1[rl];
    const float wz2r = fmaxf(Wz2[rl], 0.f);
    // ---- col-role constants (column cE of sample e) ----
    const int cE = (w << 4) + (l & 15);
    const int e  = l >> 4;
    const float wy2c = Wy2[cE];
    const float b2   = by2[0];
    const float zE   = xin[(blockIdx.x * 4 + e) * 64 + cE];
    float xcur = zE, lamE = 1.0f, prevE = 3.4e38f;

    __syncthreads();

    for (int it = 0; it < MAX_IT; ++it) {
        // ---- A: h0[rl] = softplus(Wy0 x + by0) for samples u, u+2 ----
        const uint4* xu4 = (const uint4*)&xh[u][0];
        const uint4* xv4 = (const uint4*)&xh[u + 2][0];
        const uint2* F0r = F0q + rl * 17;
        float au0 = b0r, au1 = 0.f, av0 = b0r, av1 = 0.f;
        #pragma unroll
        for (int i = 0; i < 8; ++i) {
            const uint4 xa = xu4[i], xb = xv4[i];
            const uint2 w0 = F0r[2 * i], w1 = F0r[2 * i + 1];
            au0 = FDOT2(as_h2(w0.x), as_h2(xa.x), au0);
            au0 = FDOT2(as_h2(w0.y), as_h2(xa.y), au0);
            au1 = FDOT2(as_h2(w1.x), as_h2(xa.z), au1);
            au1 = FDOT2(as_h2(w1.y), as_h2(xa.w), au1);
            av0 = FDOT2(as_h2(w0.x), as_h2(xb.x), av0);
            av0 = FDOT2(as_h2(w0.y), as_h2(xb.y), av0);
            av1 = FDOT2(as_h2(w1.x), as_h2(xb.z), av1);
            av1 = FDOT2(as_h2(w1.y), as_h2(xb.w), av1);
        }
        float sig0u, sp0u, sig0v, sp0v;
        sigsp(au0 + au1, sig0u, sp0u);
        sigsp(av0 + av1, sig0v, sp0v);
        h0h[u][rl]     = (_Float16)sp0u;
        h0h[u + 2][rl] = (_Float16)sp0v;
        __syncthreads();                       // (1) h0 ready

        // ---- B: a1[rl] = Wz1+ h0 + Wy1 x + by1 ; head partials ----
        const uint4* hu4 = (const uint4*)&h0h[u][0];
        const uint4* hv4 = (const uint4*)&h0h[u + 2][0];
        const uint2* FZr = FZq + rl * 33;
        const uint2* F1r = F1q + rl * 17;
        float bu0 = b1r, bu1 = 0.f, bv0 = b1r, bv1 = 0.f;
        #pragma unroll
        for (int i = 0; i < 16; ++i) {
            const uint4 ha = hu4[i], hb = hv4[i];
            const uint2 w0 = FZr[2 * i], w1 = FZr[2 * i + 1];
            bu0 = FDOT2(as_h2(w0.x), as_h2(ha.x), bu0);
            bu0 = FDOT2(as_h2(w0.y), as_h2(ha.y), bu0);
            bu1 = FDOT2(as_h2(w1.x), as_h2(ha.z), bu1);
            bu1 = FDOT2(as_h2(w1.y), as_h2(ha.w), bu1);
            bv0 = FDOT2(as_h2(w0.x), as_h2(hb.x), bv0);
            bv0 = FDOT2(as_h2(w0.y), as_h2(hb.y), bv0);
            bv1 = FDOT2(as_h2(w1.x), as_h2(hb.z), bv1);
            bv1 = FDOT2(as_h2(w1.y), as_h2(hb.w), bv1);
        }
        #pragma unroll
        for (int i = 0; i < 8; ++i) {
            const uint4 xa = xu4[i], xb = xv4[i];
            const uint2 w0 = F1r[2 * i], w1 = F1r[2 * i + 1];
            bu0 = FDOT2(as_h2(w0.x), as_h2(xa.x), bu0);
            bu0 = FDOT2(as_h2(w0.y), as_h2(xa.y), bu0);
            bu1 = FDOT2(as_h2(w1.x), as_h2(xa.z), bu1);
            bu1 = FDOT2(as_h2(w1.y), as_h2(xa.w), bu1);
            bv0 = FDOT2(as_h2(w0.x), as_h2(xb.x), bv0);
            bv0 = FDOT2(as_h2(w0.y), as_h2(xb.y), bv0);
            bv1 = FDOT2(as_h2(w1.x), as_h2(xb.z), bv1);
            bv1 = FDOT2(as_h2(w1.y), as_h2(xb.w), bv1);
        }
        float sig1u, h1u, sig1v, h1v;
        sigsp(bu0 + bu1, sig1u, h1u);
        sigsp(bv0 + bv1, sig1v, h1v);
        float pu = wz2r * h1u, pv = wz2r * h1v;
        if (w == 0) {   // wave 0 folds in the wy2.x term
            const unsigned wyp = wyq[l & 31];
            const unsigned xpu = ((const unsigned*)&xh[u][0])[l & 31];
            const unsigned xpv = ((const unsigned*)&xh[u + 2][0])[l & 31];
            pu = FDOT2(as_h2(wyp), as_h2(xpu), pu);
            pv = FDOT2(as_h2(wyp), as_h2(xpv), pv);
        }
        #pragma unroll
        for (int off = 16; off > 0; off >>= 1) {
            pu += __shfl_xor(pu, off, 64);
            pv += __shfl_xor(pv, off, 64);
        }
        if ((l & 31) == 0) { hp[w][u] = pu; hp[w][u + 2] = pv; }
        __syncthreads();                       // (2) head partials ready

        float s20, s21, s22, s23;
        {
            #define SIG2(s, dst) { \
                const float P = hp[0][s] + hp[1][s] + hp[2][s] + hp[3][s] + b2; \
                const float ee = __expf(-fabsf(P)); \
                const float rr = rcp_fast(1.0f + ee); \
                dst = (P >= 0.0f) ? rr : ee * rr; }
            SIG2(0, s20) SIG2(1, s21) SIG2(2, s22) SIG2(3, s23)
            #undef SIG2
        }
        const float sig2u = u ? s21 : s20;
        const float sig2v = u ? s23 : s22;
        v1h[u][rl]     = (_Float16)(sig2u * sig1u * wz2r);
        v1h[u + 2][rl] = (_Float16)(sig2v * sig1v * wz2r);
        __syncthreads();                       // (3) v1 ready

        // ---- D: v0[rl] = sig0 * (Wz1+^T v1)  +  E1: g1 = Wy1^T v1 at (cE,e) ----
        const uint4* vu4 = (const uint4*)&v1h[u][0];
        const uint4* vv4 = (const uint4*)&v1h[u + 2][0];
        const uint2* AZr = AZq + rl * 33;
        float tu0 = 0.f, tu1 = 0.f, tv0 = 0.f, tv1 = 0.f;
        #pragma unroll
        for (int i = 0; i < 16; ++i) {
            const uint4 va = vu4[i], vb = vv4[i];
            const uint2 w0 = AZr[2 * i], w1 = AZr[2 * i + 1];
            tu0 = FDOT2(as_h2(w0.x), as_h2(va.x), tu0);
            tu0 = FDOT2(as_h2(w0.y), as_h2(va.y), tu0);
            tu1 = FDOT2(as_h2(w1.x), as_h2(va.z), tu1);
            tu1 = FDOT2(as_h2(w1.y), as_h2(va.w), tu1);
            tv0 = FDOT2(as_h2(w0.x), as_h2(vb.x), tv0);
            tv0 = FDOT2(as_h2(w0.y), as_h2(vb.y), tv0);
            tv1 = FDOT2(as_h2(w1.x), as_h2(vb.z), tv1);
            tv1 = FDOT2(as_h2(w1.y), as_h2(vb.w), tv1);
        }
        v0h[u][rl]     = (_Float16)(sig0u * (tu0 + tu1));
        v0h[u + 2][rl] = (_Float16)(sig0v * (tv0 + tv1));
        // E1 (reads only v1h — ready since (3))
        const uint4* ve4 = (const uint4*)&v1h[e][0];
        const uint2* T1c = T1q + cE * 33;
        float g10 = 0.f, g11 = 0.f;
        #pragma unroll
        for (int i = 0; i < 16; ++i) {
            const uint4 va = ve4[i];
            const uint2 w0 = T1c[2 * i], w1 = T1c[2 * i + 1];
            g10 = FDOT2(as_h2(w0.x), as_h2(va.x), g10);
            g10 = FDOT2(as_h2(w0.y), as_h2(va.y), g10);
            g11 = FDOT2(as_h2(w1.x), as_h2(va.z), g11);
            g11 = FDOT2(as_h2(w1.y), as_h2(va.w), g11);
        }
        __syncthreads();                       // (4) v0 ready

        // ---- E2: g = x + sig2*wy2 + g1 + Wy0^T v0 ; residual norm ----
        const uint4* ue4 = (const uint4*)&v0h[e][0];
        const uint2* T0c = T0q + cE * 33;
        float g20 = 0.f, g21 = 0.f;
        #pragma unroll
        for (int i = 0; i < 16; ++i) {
            const uint4 va = ue4[i];
            const uint2 w0 = T0c[2 * i], w1 = T0c[2 * i + 1];
            g20 = FDOT2(as_h2(w0.x), as_h2(va.x), g20);
            g20 = FDOT2(as_h2(w0.y), as_h2(va.y), g20);
            g21 = FDOT2(as_h2(w1.x), as_h2(va.z), g21);
            g21 = FDOT2(as_h2(w1.y), as_h2(va.w), g21);
        }
        const float sig2e = (e & 1) ? ((e >> 1) ? s23 : s21) : ((e >> 1) ? s22 : s20);
        const float g = xcur + sig2e * wy2c + (g10 + g11) + (g20 + g21);
        const float resid = zE - g;
        float r2sum = resid * resid;
        #pragma unroll
        for (int off = 8; off > 0; off >>= 1) r2sum += __shfl_xor(r2sum, off, 64);
        if ((l & 15) == 0) npar[w][e] = r2sum;
        __syncthreads();                       // (5) norm partials ready

        const float n0 = sqrtf(npar[0][0] + npar[1][0] + npar[2][0] + npar[3][0]);
        const float n1 = sqrtf(npar[0][1] + npar[1][1] + npar[2][1] + npar[3][1]);
        const float n2v = sqrtf(npar[0][2] + npar[1][2] + npar[2][2] + npar[3][2]);
        const float n3 = sqrtf(npar[0][3] + npar[1][3] + npar[2][3] + npar[3][3]);
        if (n0 < TOLF && n1 < TOLF && n2v < TOLF && n3 < TOLF) break;

        const float ne = (e == 0) ? n0 : (e == 1) ? n1 : (e == 2) ? n2v : n3;
        if (ne >= TOLF) {                      // unconverged: adaptive Richardson
            if (ne > prevE * 0.999f) lamE *= 0.5f;
            const float step = fmaxf(lamE, 1.0f / (float)(it + 2));
            xcur = fmaf(step, resid, xcur);
            prevE = ne;
        }
        xh[e][cE] = (_Float16)xcur;            // frozen samples rewrite same value
        __syncthreads();                       // (6) x ready for next iter
    }

    out[(blockIdx.x * 4 + e) * 64 + cE] = xcur + zE;   // + CONVEX * z
}

extern "C" void kernel_launch(void* const* d_in, const int* in_sizes, int n_in,
                              void* d_out, int out_size, void* d_ws, size_t ws_size,
                              hipStream_t stream) {
    const float* xin = (const float*)d_in[0];
    const float* Wy0 = (const float*)d_in[1];
    const float* by0 = (const float*)d_in[2];
    const float* Wy1 = (const float*)d_in[3];
    const float* by1 = (const float*)d_in[4];
    const float* Wz1 = (const float*)d_in[5];
    const float* Wy2 = (const float*)d_in[6];
    const float* by2 = (const float*)d_in[7];
    const float* Wz2 = (const float*)d_in[8];
    float* out = (float*)d_out;

    blnn_kernel<<<dim3(NB / 4), dim3(256), 0, stream>>>(
        xin, Wy0, by0, Wy1, by1, Wz1, Wy2, by2, Wz2, out);
}

// Round 9
// 87.221 us; speedup vs baseline: 1.3168x; 1.1605x over previous
//
#include <hip/hip_runtime.h>
#include <math.h>

#define NB 1024   // batch
#define NC 64     // input dim
#define NH 128    // hidden dim
#define MAX_IT 500
#define TOLF 1e-3f

typedef _Float16 f16x8 __attribute__((ext_vector_type(8)));
typedef float    f32x4 __attribute__((ext_vector_type(4)));
typedef _Float16 h2    __attribute__((ext_vector_type(2)));

#define MFMA(a, b, c) __builtin_amdgcn_mfma_f32_16x16x32_f16((a), (b), (c), 0, 0, 0)

__device__ __forceinline__ unsigned pack_h2(float a, float b) {
    union { h2 h; unsigned u; } cv;
    cv.h.x = (_Float16)a; cv.h.y = (_Float16)b; return cv.u;
}
__device__ __forceinline__ float rcp_fast(float x) {
#if __has_builtin(__builtin_amdgcn_rcpf)
    return __builtin_amdgcn_rcpf(x);
#else
    return 1.0f / x;
#endif
}
// sigmoid + softplus sharing one exp
__device__ __forceinline__ void sigsp(float a, float& sig, float& sp) {
    const float e = __expf(-fabsf(a));
    const float r = rcp_fast(1.0f + e);
    sig = (a >= 0.0f) ? r : e * r;
    sp  = fmaxf(a, 0.0f) + __logf(1.0f + e);
}
__device__ __forceinline__ float clp(float x) { return fmaxf(x, 0.0f); }

// R9: MFMA restructure. R8 was LDS-INSTRUCTION-bound (~1200 ds_read/CU/iter).
// All matvecs -> v_mfma_f32_16x16x32_f16 over N=16 cols (4 samples x4
// replicas; replica lanes read broadcast addresses, writes predicated n<4).
// Weights staged in A-frag order (A[m=lane&15][k=quad*8+j]) -> every A-load
// is ONE coalesced ds_read_b128 carrying 1 KB. Activations per-sample
// row-major (stride 272B) -> B-frags are broadcast b128 reused across
// M-tiles. sig0/sig1 persist in regs between fwd and adjoint (same lane owns
// the same D-rows: col=lane&15, row=quad*4+reg). 6 barriers/iter, R3 solver.
__launch_bounds__(256, 1)
__global__ void blnn_kernel(const float* __restrict__ xin,
                            const float* __restrict__ Wy0,
                            const float* __restrict__ by0,
                            const float* __restrict__ Wy1,
                            const float* __restrict__ by1,
                            const float* __restrict__ Wz1,
                            const float* __restrict__ Wy2,
                            const float* __restrict__ by2,
                            const float* __restrict__ Wz2,
                            float* __restrict__ out)
{
    // A-frag weight tiles: [tile][lane] uint4 (8 fp16). tile = mt*KS + ks.
    __shared__ uint4 WA0q[16 * 64];   // Wy0   (M=128,K=64):  mt8 x ks2
    __shared__ uint4 WA1q[16 * 64];   // Wy1
    __shared__ uint4 WAZq[32 * 64];   // Wz1+  (M=128,K=128): mt8 x ks4
    __shared__ uint4 WZTq[32 * 64];   // Wz1+^T
    __shared__ uint4 W1Tq[16 * 64];   // Wy1^T (M=64,K=128):  mt4 x ks4
    __shared__ uint4 W0Tq[16 * 64];   // Wy0^T
    __shared__ __align__(16) _Float16 xact [4 * 72];   // x  per sample (stride 144B)
    __shared__ __align__(16) _Float16 h0act[4 * 136];  // h0 per sample (stride 272B)
    __shared__ __align__(16) _Float16 v1act[4 * 136];
    __shared__ __align__(16) _Float16 v0act[4 * 136];
    __shared__ __align__(16) float by0f[128], by1f[128], wz2f[128];
    __shared__ __align__(16) float hp[16], pxp[16], npar[16];   // [n][w]

    const int tid  = threadIdx.x;
    const int w    = tid >> 6;
    const int l    = tid & 63;
    const int n    = l & 15;          // MFMA col
    const int n4   = n & 3;           // real sample
    const int quad = l >> 4;
    const int blk4 = blockIdx.x * 4;

    // ---- stage weights into A-frag order ----
    for (int f = tid; f < 16 * 64; f += 256) {        // WA0 / WA1
        const int tile = f >> 6, q = f & 63;
        const int mt = tile >> 1, ks = tile & 1;
        const int row = mt * 16 + (q & 15);
        const int k0  = ks * 32 + ((q >> 4) << 3);
        const float* p0 = Wy0 + row * 64 + k0;
        WA0q[f] = make_uint4(pack_h2(p0[0], p0[1]), pack_h2(p0[2], p0[3]),
                             pack_h2(p0[4], p0[5]), pack_h2(p0[6], p0[7]));
        const float* p1 = Wy1 + row * 64 + k0;
        WA1q[f] = make_uint4(pack_h2(p1[0], p1[1]), pack_h2(p1[2], p1[3]),
                             pack_h2(p1[4], p1[5]), pack_h2(p1[6], p1[7]));
    }
    for (int f = tid; f < 32 * 64; f += 256) {        // WAZ / WZT (clip >= 0)
        const int tile = f >> 6, q = f & 63;
        const int mt = tile >> 2, ks = tile & 3;
        const int row = mt * 16 + (q & 15);
        const int k0  = ks * 32 + ((q >> 4) << 3);
        const float* p = Wz1 + row * 128 + k0;
        WAZq[f] = make_uint4(pack_h2(clp(p[0]), clp(p[1])), pack_h2(clp(p[2]), clp(p[3])),
                             pack_h2(clp(p[4]), clp(p[5])), pack_h2(clp(p[6]), clp(p[7])));
        const float* pt = Wz1 + k0 * 128 + row;       // (Wz1^T)[row][k0+j] = Wz1[k0+j][row]
        WZTq[f] = make_uint4(pack_h2(clp(pt[0]),   clp(pt[128])),
                             pack_h2(clp(pt[256]), clp(pt[384])),
                             pack_h2(clp(pt[512]), clp(pt[640])),
                             pack_h2(clp(pt[768]), clp(pt[896])));
    }
    for (int f = tid; f < 16 * 64; f += 256) {        // W1T / W0T
        const int tile = f >> 6, q = f & 63;
        const int mt = tile >> 2, ks = tile & 3;
        const int rowT = mt * 16 + (q & 15);          // c in 0..63
        const int k0   = ks * 32 + ((q >> 4) << 3);   // original row
        const float* p1 = Wy1 + k0 * 64 + rowT;
        W1Tq[f] = make_uint4(pack_h2(p1[0],   p1[64]),  pack_h2(p1[128], p1[192]),
                             pack_h2(p1[256], p1[320]), pack_h2(p1[384], p1[448]));
        const float* p0 = Wy0 + k0 * 64 + rowT;
        W0Tq[f] = make_uint4(pack_h2(p0[0],   p0[64]),  pack_h2(p0[128], p0[192]),
                             pack_h2(p0[256], p0[320]), pack_h2(p0[384], p0[448]));
    }
    if (tid < 128) {
        by0f[tid] = by0[tid];
        by1f[tid] = by1[tid];
        wz2f[tid] = fmaxf(Wz2[tid], 0.0f);
    }
    {   // x0 = z into act layout
        const int nn = tid >> 6, cc = tid & 63;
        xact[nn * 72 + cc] = (_Float16)xin[(blk4 + nn) * 64 + cc];
    }

    // ---- per-lane col-role state: rows c = 16w + quad*4 + r, sample n4 ----
    const float4 z4  = ((const float4*)xin)[(blk4 + n4) * 16 + w * 4 + quad];
    const float4 wy4 = ((const float4*)Wy2)[w * 4 + quad];
    float zr[4]   = {z4.x, z4.y, z4.z, z4.w};
    float wy2r[4] = {wy4.x, wy4.y, wy4.z, wy4.w};
    float xcur[4] = {zr[0], zr[1], zr[2], zr[3]};
    float lamE = 1.0f, prevE = 3.4e38f;
    const float b2 = by2[0];

    {   // px = sum_c wy2[c]*x[c] for first iteration
        float pxs = wy2r[0]*xcur[0] + wy2r[1]*xcur[1] + wy2r[2]*xcur[2] + wy2r[3]*xcur[3];
        pxs += __shfl_xor(pxs, 16, 64);
        pxs += __shfl_xor(pxs, 32, 64);
        if (l < 4) pxp[l * 4 + w] = pxs;
    }
    __syncthreads();

    const f16x8* WA0v = (const f16x8*)WA0q;
    const f16x8* WA1v = (const f16x8*)WA1q;
    const f16x8* WAZv = (const f16x8*)WAZq;
    const f16x8* WZTv = (const f16x8*)WZTq;
    const f16x8* W1Tv = (const f16x8*)W1Tq;
    const f16x8* W0Tv = (const f16x8*)W0Tq;
    const float4* by0v = (const float4*)by0f;
    const float4* by1v = (const float4*)by1f;
    const float4* wz2v = (const float4*)wz2f;
    const _Float16* xrow  = xact  + n4 * 72;
    const _Float16* h0row = h0act + n4 * 136;
    const _Float16* v1row = v1act + n4 * 136;
    const _Float16* v0row = v0act + n4 * 136;

    float sig0[2][4], sig1[2][4], wzr[2][4];
    float sg2 = 0.0f;

    for (int it = 0; it < MAX_IT; ++it) {
        // ---- P1: preact0 = Wy0 x + by0 -> h0, sig0 ----
        f16x8 bx0 = *(const f16x8*)(xrow + quad * 8);
        f16x8 bx1 = *(const f16x8*)(xrow + 32 + quad * 8);
        #pragma unroll
        for (int mi = 0; mi < 2; ++mi) {
            const int mt = w + 4 * mi;
            f32x4 acc = {0.f, 0.f, 0.f, 0.f};
            acc = MFMA(WA0v[(mt * 2 + 0) * 64 + l], bx0, acc);
            acc = MFMA(WA0v[(mt * 2 + 1) * 64 + l], bx1, acc);
            const float4 bb = by0v[mt * 4 + quad];
            float sp0, sp1, sp2, sp3;
            sigsp(acc[0] + bb.x, sig0[mi][0], sp0);
            sigsp(acc[1] + bb.y, sig0[mi][1], sp1);
            sigsp(acc[2] + bb.z, sig0[mi][2], sp2);
            sigsp(acc[3] + bb.w, sig0[mi][3], sp3);
            if (n < 4)
                *(uint2*)&h0act[n4 * 136 + mt * 16 + quad * 4] =
                    make_uint2(pack_h2(sp0, sp1), pack_h2(sp2, sp3));
        }
        __syncthreads();   // (1) h0 ready

        // ---- P2: preact1 = Wz1+ h0 + Wy1 x + by1 -> sig1, h1, head ----
        f16x8 bh0 = *(const f16x8*)(h0row + quad * 8);
        f16x8 bh1 = *(const f16x8*)(h0row + 32 + quad * 8);
        f16x8 bh2 = *(const f16x8*)(h0row + 64 + quad * 8);
        f16x8 bh3 = *(const f16x8*)(h0row + 96 + quad * 8);
        float hsum = 0.0f;
        #pragma unroll
        for (int mi = 0; mi < 2; ++mi) {
            const int mt = w + 4 * mi;
            f32x4 acc = {0.f, 0.f, 0.f, 0.f};
            acc = MFMA(WAZv[(mt * 4 + 0) * 64 + l], bh0, acc);
            acc = MFMA(WAZv[(mt * 4 + 1) * 64 + l], bh1, acc);
            acc = MFMA(WAZv[(mt * 4 + 2) * 64 + l], bh2, acc);
            acc = MFMA(WAZv[(mt * 4 + 3) * 64 + l], bh3, acc);
            acc = MFMA(WA1v[(mt * 2 + 0) * 64 + l], bx0, acc);
            acc = MFMA(WA1v[(mt * 2 + 1) * 64 + l], bx1, acc);
            const float4 bb  = by1v[mt * 4 + quad];
            const float4 wzq = wz2v[mt * 4 + quad];
            float h1v;
            sigsp(acc[0] + bb.x, sig1[mi][0], h1v); hsum = fmaf(wzq.x, h1v, hsum);
            sigsp(acc[1] + bb.y, sig1[mi][1], h1v); hsum = fmaf(wzq.y, h1v, hsum);
            sigsp(acc[2] + bb.z, sig1[mi][2], h1v); hsum = fmaf(wzq.z, h1v, hsum);
            sigsp(acc[3] + bb.w, sig1[mi][3], h1v); hsum = fmaf(wzq.w, h1v, hsum);
            wzr[mi][0] = wzq.x; wzr[mi][1] = wzq.y; wzr[mi][2] = wzq.z; wzr[mi][3] = wzq.w;
        }
        hsum += __shfl_xor(hsum, 16, 64);
        hsum += __shfl_xor(hsum, 32, 64);
        if (l < 4) hp[l * 4 + w] = hsum;
        __syncthreads();   // (2) head partials ready

        {
            const float4 hv = ((const float4*)hp)[n4];
            const float4 pv = ((const float4*)pxp)[n4];
            const float P = hv.x + hv.y + hv.z + hv.w + pv.x + pv.y + pv.z + pv.w + b2;
            const float e = __expf(-fabsf(P));
            const float r = rcp_fast(1.0f + e);
            sg2 = (P >= 0.0f) ? r : e * r;
        }
        #pragma unroll
        for (int mi = 0; mi < 2; ++mi) {
            const int mt = w + 4 * mi;
            const float a0 = sg2 * sig1[mi][0] * wzr[mi][0];
            const float a1 = sg2 * sig1[mi][1] * wzr[mi][1];
            const float a2 = sg2 * sig1[mi][2] * wzr[mi][2];
            const float a3 = sg2 * sig1[mi][3] * wzr[mi][3];
            if (n < 4)
                *(uint2*)&v1act[n4 * 136 + mt * 16 + quad * 4] =
                    make_uint2(pack_h2(a0, a1), pack_h2(a2, a3));
        }
        __syncthreads();   // (3) v1 ready

        // ---- P4: v0 = sig0 .* (Wz1+^T v1)   +   P6a: Wy1^T v1 ----
        f16x8 bv10 = *(const f16x8*)(v1row + quad * 8);
        f16x8 bv11 = *(const f16x8*)(v1row + 32 + quad * 8);
        f16x8 bv12 = *(const f16x8*)(v1row + 64 + quad * 8);
        f16x8 bv13 = *(const f16x8*)(v1row + 96 + quad * 8);
        #pragma unroll
        for (int mi = 0; mi < 2; ++mi) {
            const int mt = w + 4 * mi;
            f32x4 acc = {0.f, 0.f, 0.f, 0.f};
            acc = MFMA(WZTv[(mt * 4 + 0) * 64 + l], bv10, acc);
            acc = MFMA(WZTv[(mt * 4 + 1) * 64 + l], bv11, acc);
            acc = MFMA(WZTv[(mt * 4 + 2) * 64 + l], bv12, acc);
            acc = MFMA(WZTv[(mt * 4 + 3) * 64 + l], bv13, acc);
            const float a0 = sig0[mi][0] * acc[0];
            const float a1 = sig0[mi][1] * acc[1];
            const float a2 = sig0[mi][2] * acc[2];
            const float a3 = sig0[mi][3] * acc[3];
            if (n < 4)
                *(uint2*)&v0act[n4 * 136 + mt * 16 + quad * 4] =
                    make_uint2(pack_h2(a0, a1), pack_h2(a2, a3));
        }
        f32x4 accg = {0.f, 0.f, 0.f, 0.f};
        accg = MFMA(W1Tv[(w * 4 + 0) * 64 + l], bv10, accg);
        accg = MFMA(W1Tv[(w * 4 + 1) * 64 + l], bv11, accg);
        accg = MFMA(W1Tv[(w * 4 + 2) * 64 + l], bv12, accg);
        accg = MFMA(W1Tv[(w * 4 + 3) * 64 + l], bv13, accg);
        __syncthreads();   // (4) v0 ready

        // ---- P6b: g = x + sig2*wy2 + Wy1^T v1 + Wy0^T v0 ; residual ----
        f16x8 bv00 = *(const f16x8*)(v0row + quad * 8);
        f16x8 bv01 = *(const f16x8*)(v0row + 32 + quad * 8);
        f16x8 bv02 = *(const f16x8*)(v0row + 64 + quad * 8);
        f16x8 bv03 = *(const f16x8*)(v0row + 96 + quad * 8);
        accg = MFMA(W0Tv[(w * 4 + 0) * 64 + l], bv00, accg);
        accg = MFMA(W0Tv[(w * 4 + 1) * 64 + l], bv01, accg);
        accg = MFMA(W0Tv[(w * 4 + 2) * 64 + l], bv02, accg);
        accg = MFMA(W0Tv[(w * 4 + 3) * 64 + l], bv03, accg);
        float resid[4];
        float r2 = 0.0f;
        #pragma unroll
        for (int r = 0; r < 4; ++r) {
            const float g = xcur[r] + sg2 * wy2r[r] + accg[r];
            resid[r] = zr[r] - g;
            r2 = fmaf(resid[r], resid[r], r2);
        }
        r2 += __shfl_xor(r2, 16, 64);
        r2 += __shfl_xor(r2, 32, 64);
        if (l < 4) npar[l * 4 + w] = r2;
        __syncthreads();   // (5) norm partials ready

        const float4 q0 = ((const float4*)npar)[0];
        const float4 q1 = ((const float4*)npar)[1];
        const float4 q2 = ((const float4*)npar)[2];
        const float4 q3 = ((const float4*)npar)[3];
        const float s0 = q0.x + q0.y + q0.z + q0.w;
        const float s1 = q1.x + q1.y + q1.z + q1.w;
        const float s2 = q2.x + q2.y + q2.z + q2.w;
        const float s3 = q3.x + q3.y + q3.z + q3.w;
        const float T2 = TOLF * TOLF;
        if (s0 < T2 && s1 < T2 && s2 < T2 && s3 < T2) break;   // uniform

        const float myn2 = (n4 == 0) ? s0 : (n4 == 1) ? s1 : (n4 == 2) ? s2 : s3;
        const float ne = sqrtf(myn2);
        if (ne >= TOLF) {                    // adaptive Richardson (R3 solver)
            if (ne > prevE * 0.999f) lamE *= 0.5f;
            const float step = fmaxf(lamE, 1.0f / (float)(it + 2));
            #pragma unroll
            for (int r = 0; r < 4; ++r) xcur[r] = fmaf(step, resid[r], xcur[r]);
            prevE = ne;
        }
        {   // px partial for next iter + x writeback
            float pxs = wy2r[0]*xcur[0] + wy2r[1]*xcur[1] + wy2r[2]*xcur[2] + wy2r[3]*xcur[3];
            pxs += __shfl_xor(pxs, 16, 64);
            pxs += __shfl_xor(pxs, 32, 64);
            if (l < 4) pxp[l * 4 + w] = pxs;
        }
        if (n < 4)
            *(uint2*)&xact[n4 * 72 + w * 16 + quad * 4] =
                make_uint2(pack_h2(xcur[0], xcur[1]), pack_h2(xcur[2], xcur[3]));
        __syncthreads();   // (6) x ready
    }

    if (n < 4) {
        float4 o;
        o.x = xcur[0] + zr[0]; o.y = xcur[1] + zr[1];
        o.z = xcur[2] + zr[2]; o.w = xcur[3] + zr[3];
        ((float4*)out)[(blk4 + n4) * 16 + w * 4 + quad] = o;   // + CONVEX*z
    }
}

extern "C" void kernel_launch(void* const* d_in, const int* in_sizes, int n_in,
                              void* d_out, int out_size, void* d_ws, size_t ws_size,
                              hipStream_t stream) {
    const float* xin = (const float*)d_in[0];
    const float* Wy0 = (const float*)d_in[1];
    const float* by0 = (const float*)d_in[2];
    const float* Wy1 = (const float*)d_in[3];
    const float* by1 = (const float*)d_in[4];
    const float* Wz1 = (const float*)d_in[5];
    const float* Wy2 = (const float*)d_in[6];
    const float* by2 = (const float*)d_in[7];
    const float* Wz2 = (const float*)d_in[8];
    float* out = (float*)d_out;

    blnn_kernel<<<dim3(NB / 4), dim3(256), 0, stream>>>(
        xin, Wy0, by0, Wy1, by1, Wz1, Wy2, by2, Wz2, out);
}

// Round 10
// 86.948 us; speedup vs baseline: 1.3210x; 1.0031x over previous
//
#include <hip/hip_runtime.h>
#include <math.h>

#define NB 1024   // batch
#define NC 64     // input dim
#define NH 128    // hidden dim
#define MAX_IT 500
#define TOLF 1e-3f

typedef _Float16 f16x8 __attribute__((ext_vector_type(8)));
typedef float    f32x4 __attribute__((ext_vector_type(4)));
typedef _Float16 h2    __attribute__((ext_vector_type(2)));

#define MFMA(a, b, c) __builtin_amdgcn_mfma_f32_16x16x32_f16((a), (b), (c), 0, 0, 0)

__device__ __forceinline__ unsigned pack_h2(float a, float b) {
    union { h2 h; unsigned u; } cv;
    cv.h.x = (_Float16)a; cv.h.y = (_Float16)b; return cv.u;
}
__device__ __forceinline__ float rcp_fast(float x) {
#if __has_builtin(__builtin_amdgcn_rcpf)
    return __builtin_amdgcn_rcpf(x);
#else
    return 1.0f / x;
#endif
}
// sigmoid + softplus sharing one exp
__device__ __forceinline__ void sigsp(float a, float& sig, float& sp) {
    const float e = __expf(-fabsf(a));
    const float r = rcp_fast(1.0f + e);
    sig = (a >= 0.0f) ? r : e * r;
    sp  = fmaxf(a, 0.0f) + __logf(1.0f + e);
}
__device__ __forceinline__ float clp(float x) { return fmaxf(x, 0.0f); }

// R10: R9's MFMA structure was LDS-issue-bound again (184 b128/CU/iter, ~86%
// of the pipe). Each wave's A-frag weight tiles are iteration-invariant
// (mt = f(w)), so ALL 32 tiles (128 VGPRs/lane) are hoisted into named f16x8
// registers before the loop and fed to MFMA directly. Loop LDS = activations
// only (~56 b128 + writes per CU). Unlike R5-R7's VALU-dot2 pins, MFMA eats
// A-operands from VGPR/AGPR natively, so there is no copy-back failure mode.
__launch_bounds__(256, 1)
__global__ void blnn_kernel(const float* __restrict__ xin,
                            const float* __restrict__ Wy0,
                            const float* __restrict__ by0,
                            const float* __restrict__ Wy1,
                            const float* __restrict__ by1,
                            const float* __restrict__ Wz1,
                            const float* __restrict__ Wy2,
                            const float* __restrict__ by2,
                            const float* __restrict__ Wz2,
                            float* __restrict__ out)
{
    // A-frag weight tiles: [tile][lane] uint4 (8 fp16). tile = mt*KS + ks.
    __shared__ uint4 WA0q[16 * 64];   // Wy0   (M=128,K=64):  mt8 x ks2
    __shared__ uint4 WA1q[16 * 64];   // Wy1
    __shared__ uint4 WAZq[32 * 64];   // Wz1+  (M=128,K=128): mt8 x ks4
    __shared__ uint4 WZTq[32 * 64];   // Wz1+^T
    __shared__ uint4 W1Tq[16 * 64];   // Wy1^T (M=64,K=128):  mt4 x ks4
    __shared__ uint4 W0Tq[16 * 64];   // Wy0^T
    __shared__ __align__(16) _Float16 xact [4 * 72];   // x  per sample
    __shared__ __align__(16) _Float16 h0act[4 * 136];  // h0 per sample
    __shared__ __align__(16) _Float16 v1act[4 * 136];
    __shared__ __align__(16) _Float16 v0act[4 * 136];
    __shared__ __align__(16) float by0f[128], by1f[128], wz2f[128];
    __shared__ __align__(16) float hp[16], pxp[16], npar[16];   // [n][w]

    const int tid  = threadIdx.x;
    const int w    = tid >> 6;
    const int l    = tid & 63;
    const int n    = l & 15;          // MFMA col
    const int n4   = n & 3;           // real sample
    const int quad = l >> 4;
    const int blk4 = blockIdx.x * 4;

    // ---- stage weights into A-frag order ----
    for (int f = tid; f < 16 * 64; f += 256) {        // WA0 / WA1
        const int tile = f >> 6, q = f & 63;
        const int mt = tile >> 1, ks = tile & 1;
        const int row = mt * 16 + (q & 15);
        const int k0  = ks * 32 + ((q >> 4) << 3);
        const float* p0 = Wy0 + row * 64 + k0;
        WA0q[f] = make_uint4(pack_h2(p0[0], p0[1]), pack_h2(p0[2], p0[3]),
                             pack_h2(p0[4], p0[5]), pack_h2(p0[6], p0[7]));
        const float* p1 = Wy1 + row * 64 + k0;
        WA1q[f] = make_uint4(pack_h2(p1[0], p1[1]), pack_h2(p1[2], p1[3]),
                             pack_h2(p1[4], p1[5]), pack_h2(p1[6], p1[7]));
    }
    for (int f = tid; f < 32 * 64; f += 256) {        // WAZ / WZT (clip >= 0)
        const int tile = f >> 6, q = f & 63;
        const int mt = tile >> 2, ks = tile & 3;
        const int row = mt * 16 + (q & 15);
        const int k0  = ks * 32 + ((q >> 4) << 3);
        const float* p = Wz1 + row * 128 + k0;
        WAZq[f] = make_uint4(pack_h2(clp(p[0]), clp(p[1])), pack_h2(clp(p[2]), clp(p[3])),
                             pack_h2(clp(p[4]), clp(p[5])), pack_h2(clp(p[6]), clp(p[7])));
        const float* pt = Wz1 + k0 * 128 + row;       // (Wz1^T)[row][k0+j]
        WZTq[f] = make_uint4(pack_h2(clp(pt[0]),   clp(pt[128])),
                             pack_h2(clp(pt[256]), clp(pt[384])),
                             pack_h2(clp(pt[512]), clp(pt[640])),
                             pack_h2(clp(pt[768]), clp(pt[896])));
    }
    for (int f = tid; f < 16 * 64; f += 256) {        // W1T / W0T
        const int tile = f >> 6, q = f & 63;
        const int mt = tile >> 2, ks = tile & 3;
        const int rowT = mt * 16 + (q & 15);          // c in 0..63
        const int k0   = ks * 32 + ((q >> 4) << 3);   // original row
        const float* p1 = Wy1 + k0 * 64 + rowT;
        W1Tq[f] = make_uint4(pack_h2(p1[0],   p1[64]),  pack_h2(p1[128], p1[192]),
                             pack_h2(p1[256], p1[320]), pack_h2(p1[384], p1[448]));
        const float* p0 = Wy0 + k0 * 64 + rowT;
        W0Tq[f] = make_uint4(pack_h2(p0[0],   p0[64]),  pack_h2(p0[128], p0[192]),
                             pack_h2(p0[256], p0[320]), pack_h2(p0[384], p0[448]));
    }
    if (tid < 128) {
        by0f[tid] = by0[tid];
        by1f[tid] = by1[tid];
        wz2f[tid] = fmaxf(Wz2[tid], 0.0f);
    }
    {   // x0 = z into act layout
        const int nn = tid >> 6, cc = tid & 63;
        xact[nn * 72 + cc] = (_Float16)xin[(blk4 + nn) * 64 + cc];
    }

    // ---- per-lane col-role state: rows c = 16w + quad*4 + r, sample n4 ----
    const float4 z4  = ((const float4*)xin)[(blk4 + n4) * 16 + w * 4 + quad];
    const float4 wy4 = ((const float4*)Wy2)[w * 4 + quad];
    float zr[4]   = {z4.x, z4.y, z4.z, z4.w};
    float wy2r[4] = {wy4.x, wy4.y, wy4.z, wy4.w};
    float xcur[4] = {zr[0], zr[1], zr[2], zr[3]};
    float lamE = 1.0f, prevE = 3.4e38f;
    const float b2 = by2[0];

    {   // px = sum_c wy2[c]*x[c] for first iteration
        float pxs = wy2r[0]*xcur[0] + wy2r[1]*xcur[1] + wy2r[2]*xcur[2] + wy2r[3]*xcur[3];
        pxs += __shfl_xor(pxs, 16, 64);
        pxs += __shfl_xor(pxs, 32, 64);
        if (l < 4) pxp[l * 4 + w] = pxs;
    }
    __syncthreads();

    const f16x8* WA0v = (const f16x8*)WA0q;
    const f16x8* WA1v = (const f16x8*)WA1q;
    const f16x8* WAZv = (const f16x8*)WAZq;
    const f16x8* WZTv = (const f16x8*)WZTq;
    const f16x8* W1Tv = (const f16x8*)W1Tq;
    const f16x8* W0Tv = (const f16x8*)W0Tq;
    const float4* by0v = (const float4*)by0f;
    const float4* by1v = (const float4*)by1f;
    const float4* wz2v = (const float4*)wz2f;
    const _Float16* xrow  = xact  + n4 * 72;
    const _Float16* h0row = h0act + n4 * 136;
    const _Float16* v1row = v1act + n4 * 136;
    const _Float16* v0row = v0act + n4 * 136;

    // ---- hoist ALL per-wave A-frag tiles into registers (iteration-invariant)
    const f16x8 fa0_00 = WA0v[((w    ) * 2 + 0) * 64 + l];
    const f16x8 fa0_01 = WA0v[((w    ) * 2 + 1) * 64 + l];
    const f16x8 fa0_10 = WA0v[((w + 4) * 2 + 0) * 64 + l];
    const f16x8 fa0_11 = WA0v[((w + 4) * 2 + 1) * 64 + l];
    const f16x8 fa1_00 = WA1v[((w    ) * 2 + 0) * 64 + l];
    const f16x8 fa1_01 = WA1v[((w    ) * 2 + 1) * 64 + l];
    const f16x8 fa1_10 = WA1v[((w + 4) * 2 + 0) * 64 + l];
    const f16x8 fa1_11 = WA1v[((w + 4) * 2 + 1) * 64 + l];
    const f16x8 faz_00 = WAZv[((w    ) * 4 + 0) * 64 + l];
    const f16x8 faz_01 = WAZv[((w    ) * 4 + 1) * 64 + l];
    const f16x8 faz_02 = WAZv[((w    ) * 4 + 2) * 64 + l];
    const f16x8 faz_03 = WAZv[((w    ) * 4 + 3) * 64 + l];
    const f16x8 faz_10 = WAZv[((w + 4) * 4 + 0) * 64 + l];
    const f16x8 faz_11 = WAZv[((w + 4) * 4 + 1) * 64 + l];
    const f16x8 faz_12 = WAZv[((w + 4) * 4 + 2) * 64 + l];
    const f16x8 faz_13 = WAZv[((w + 4) * 4 + 3) * 64 + l];
    const f16x8 fzt_00 = WZTv[((w    ) * 4 + 0) * 64 + l];
    const f16x8 fzt_01 = WZTv[((w    ) * 4 + 1) * 64 + l];
    const f16x8 fzt_02 = WZTv[((w    ) * 4 + 2) * 64 + l];
    const f16x8 fzt_03 = WZTv[((w    ) * 4 + 3) * 64 + l];
    const f16x8 fzt_10 = WZTv[((w + 4) * 4 + 0) * 64 + l];
    const f16x8 fzt_11 = WZTv[((w + 4) * 4 + 1) * 64 + l];
    const f16x8 fzt_12 = WZTv[((w + 4) * 4 + 2) * 64 + l];
    const f16x8 fzt_13 = WZTv[((w + 4) * 4 + 3) * 64 + l];
    const f16x8 ft1_0  = W1Tv[(w * 4 + 0) * 64 + l];
    const f16x8 ft1_1  = W1Tv[(w * 4 + 1) * 64 + l];
    const f16x8 ft1_2  = W1Tv[(w * 4 + 2) * 64 + l];
    const f16x8 ft1_3  = W1Tv[(w * 4 + 3) * 64 + l];
    const f16x8 ft0_0  = W0Tv[(w * 4 + 0) * 64 + l];
    const f16x8 ft0_1  = W0Tv[(w * 4 + 1) * 64 + l];
    const f16x8 ft0_2  = W0Tv[(w * 4 + 2) * 64 + l];
    const f16x8 ft0_3  = W0Tv[(w * 4 + 3) * 64 + l];

    float sig0[2][4], sig1[2][4], wzr[2][4];
    float sg2 = 0.0f;

    for (int it = 0; it < MAX_IT; ++it) {
        // ---- P1: preact0 = Wy0 x + by0 -> h0, sig0 ----
        f16x8 bx0 = *(const f16x8*)(xrow + quad * 8);
        f16x8 bx1 = *(const f16x8*)(xrow + 32 + quad * 8);
#define P1_BODY(MI, TA, TB) { \
        const int mt = w + 4 * MI; \
        f32x4 acc = {0.f, 0.f, 0.f, 0.f}; \
        acc = MFMA(TA, bx0, acc); \
        acc = MFMA(TB, bx1, acc); \
        const float4 bb = by0v[mt * 4 + quad]; \
        float sp0, sp1, sp2, sp3; \
        sigsp(acc[0] + bb.x, sig0[MI][0], sp0); \
        sigsp(acc[1] + bb.y, sig0[MI][1], sp1); \
        sigsp(acc[2] + bb.z, sig0[MI][2], sp2); \
        sigsp(acc[3] + bb.w, sig0[MI][3], sp3); \
        if (n < 4) \
            *(uint2*)&h0act[n4 * 136 + mt * 16 + quad * 4] = \
                make_uint2(pack_h2(sp0, sp1), pack_h2(sp2, sp3)); }
        P1_BODY(0, fa0_00, fa0_01)
        P1_BODY(1, fa0_10, fa0_11)
#undef P1_BODY
        __syncthreads();   // (1) h0 ready

        // ---- P2: preact1 = Wz1+ h0 + Wy1 x + by1 -> sig1, h1, head ----
        f16x8 bh0 = *(const f16x8*)(h0row + quad * 8);
        f16x8 bh1 = *(const f16x8*)(h0row + 32 + quad * 8);
        f16x8 bh2 = *(const f16x8*)(h0row + 64 + quad * 8);
        f16x8 bh3 = *(const f16x8*)(h0row + 96 + quad * 8);
        float hsum = 0.0f;
#define P2_BODY(MI, Z0, Z1, Z2, Z3, A0, A1) { \
        const int mt = w + 4 * MI; \
        f32x4 acc = {0.f, 0.f, 0.f, 0.f}; \
        acc = MFMA(Z0, bh0, acc); \
        acc = MFMA(Z1, bh1, acc); \
        acc = MFMA(Z2, bh2, acc); \
        acc = MFMA(Z3, bh3, acc); \
        acc = MFMA(A0, bx0, acc); \
        acc = MFMA(A1, bx1, acc); \
        const float4 bb  = by1v[mt * 4 + quad]; \
        const float4 wzq = wz2v[mt * 4 + quad]; \
        float h1v; \
        sigsp(acc[0] + bb.x, sig1[MI][0], h1v); hsum = fmaf(wzq.x, h1v, hsum); \
        sigsp(acc[1] + bb.y, sig1[MI][1], h1v); hsum = fmaf(wzq.y, h1v, hsum); \
        sigsp(acc[2] + bb.z, sig1[MI][2], h1v); hsum = fmaf(wzq.z, h1v, hsum); \
        sigsp(acc[3] + bb.w, sig1[MI][3], h1v); hsum = fmaf(wzq.w, h1v, hsum); \
        wzr[MI][0] = wzq.x; wzr[MI][1] = wzq.y; wzr[MI][2] = wzq.z; wzr[MI][3] = wzq.w; }
        P2_BODY(0, faz_00, faz_01, faz_02, faz_03, fa1_00, fa1_01)
        P2_BODY(1, faz_10, faz_11, faz_12, faz_13, fa1_10, fa1_11)
#undef P2_BODY
        hsum += __shfl_xor(hsum, 16, 64);
        hsum += __shfl_xor(hsum, 32, 64);
        if (l < 4) hp[l * 4 + w] = hsum;
        __syncthreads();   // (2) head partials ready

        {
            const float4 hv = ((const float4*)hp)[n4];
            const float4 pv = ((const float4*)pxp)[n4];
            const float P = hv.x + hv.y + hv.z + hv.w + pv.x + pv.y + pv.z + pv.w + b2;
            const float e = __expf(-fabsf(P));
            const float r = rcp_fast(1.0f + e);
            sg2 = (P >= 0.0f) ? r : e * r;
        }
        #pragma unroll
        for (int mi = 0; mi < 2; ++mi) {
            const int mt = w + 4 * mi;
            const float a0 = sg2 * sig1[mi][0] * wzr[mi][0];
            const float a1 = sg2 * sig1[mi][1] * wzr[mi][1];
            const float a2 = sg2 * sig1[mi][2] * wzr[mi][2];
            const float a3 = sg2 * sig1[mi][3] * wzr[mi][3];
            if (n < 4)
                *(uint2*)&v1act[n4 * 136 + mt * 16 + quad * 4] =
                    make_uint2(pack_h2(a0, a1), pack_h2(a2, a3));
        }
        __syncthreads();   // (3) v1 ready

        // ---- P4: v0 = sig0 .* (Wz1+^T v1)   +   P6a: Wy1^T v1 ----
        f16x8 bv10 = *(const f16x8*)(v1row + quad * 8);
        f16x8 bv11 = *(const f16x8*)(v1row + 32 + quad * 8);
        f16x8 bv12 = *(const f16x8*)(v1row + 64 + quad * 8);
        f16x8 bv13 = *(const f16x8*)(v1row + 96 + quad * 8);
#define P4_BODY(MI, Z0, Z1, Z2, Z3) { \
        const int mt = w + 4 * MI; \
        f32x4 acc = {0.f, 0.f, 0.f, 0.f}; \
        acc = MFMA(Z0, bv10, acc); \
        acc = MFMA(Z1, bv11, acc); \
        acc = MFMA(Z2, bv12, acc); \
        acc = MFMA(Z3, bv13, acc); \
        const float a0 = sig0[MI][0] * acc[0]; \
        const float a1 = sig0[MI][1] * acc[1]; \
        const float a2 = sig0[MI][2] * acc[2]; \
        const float a3 = sig0[MI][3] * acc[3]; \
        if (n < 4) \
            *(uint2*)&v0act[n4 * 136 + mt * 16 + quad * 4] = \
                make_uint2(pack_h2(a0, a1), pack_h2(a2, a3)); }
        P4_BODY(0, fzt_00, fzt_01, fzt_02, fzt_03)
        P4_BODY(1, fzt_10, fzt_11, fzt_12, fzt_13)
#undef P4_BODY
        f32x4 accg = {0.f, 0.f, 0.f, 0.f};
        accg = MFMA(ft1_0, bv10, accg);
        accg = MFMA(ft1_1, bv11, accg);
        accg = MFMA(ft1_2, bv12, accg);
        accg = MFMA(ft1_3, bv13, accg);
        __syncthreads();   // (4) v0 ready

        // ---- P6b: g = x + sig2*wy2 + Wy1^T v1 + Wy0^T v0 ; residual ----
        f16x8 bv00 = *(const f16x8*)(v0row + quad * 8);
        f16x8 bv01 = *(const f16x8*)(v0row + 32 + quad * 8);
        f16x8 bv02 = *(const f16x8*)(v0row + 64 + quad * 8);
        f16x8 bv03 = *(const f16x8*)(v0row + 96 + quad * 8);
        accg = MFMA(ft0_0, bv00, accg);
        accg = MFMA(ft0_1, bv01, accg);
        accg = MFMA(ft0_2, bv02, accg);
        accg = MFMA(ft0_3, bv03, accg);
        float resid[4];
        float r2 = 0.0f;
        #pragma unroll
        for (int r = 0; r < 4; ++r) {
            const float g = xcur[r] + sg2 * wy2r[r] + accg[r];
            resid[r] = zr[r] - g;
            r2 = fmaf(resid[r], resid[r], r2);
        }
        r2 += __shfl_xor(r2, 16, 64);
        r2 += __shfl_xor(r2, 32, 64);
        if (l < 4) npar[l * 4 + w] = r2;
        __syncthreads();   // (5) norm partials ready

        const float4 q0 = ((const float4*)npar)[0];
        const float4 q1 = ((const float4*)npar)[1];
        const float4 q2 = ((const float4*)npar)[2];
        const float4 q3 = ((const float4*)npar)[3];
        const float s0 = q0.x + q0.y + q0.z + q0.w;
        const float s1 = q1.x + q1.y + q1.z + q1.w;
        const float s2 = q2.x + q2.y + q2.z + q2.w;
        const float s3 = q3.x + q3.y + q3.z + q3.w;
        const float T2 = TOLF * TOLF;
        if (s0 < T2 && s1 < T2 && s2 < T2 && s3 < T2) break;   // uniform

        const float myn2 = (n4 == 0) ? s0 : (n4 == 1) ? s1 : (n4 == 2) ? s2 : s3;
        const float ne = sqrtf(myn2);
        if (ne >= TOLF) {                    // adaptive Richardson (R3 solver)
            if (ne > prevE * 0.999f) lamE *= 0.5f;
            const float step = fmaxf(lamE, 1.0f / (float)(it + 2));
            #pragma unroll
            for (int r = 0; r < 4; ++r) xcur[r] = fmaf(step, resid[r], xcur[r]);
            prevE = ne;
        }
        {   // px partial for next iter + x writeback
            float pxs = wy2r[0]*xcur[0] + wy2r[1]*xcur[1] + wy2r[2]*xcur[2] + wy2r[3]*xcur[3];
            pxs += __shfl_xor(pxs, 16, 64);
            pxs += __shfl_xor(pxs, 32, 64);
            if (l < 4) pxp[l * 4 + w] = pxs;
        }
        if (n < 4)
            *(uint2*)&xact[n4 * 72 + w * 16 + quad * 4] =
                make_uint2(pack_h2(xcur[0], xcur[1]), pack_h2(xcur[2], xcur[3]));
        __syncthreads();   // (6) x ready
    }

    if (n < 4) {
        float4 o;
        o.x = xcur[0] + zr[0]; o.y = xcur[1] + zr[1];
        o.z = xcur[2] + zr[2]; o.w = xcur[3] + zr[3];
        ((float4*)out)[(blk4 + n4) * 16 + w * 4 + quad] = o;   // + CONVEX*z
    }
}

extern "C" void kernel_launch(void* const* d_in, const int* in_sizes, int n_in,
                              void* d_out, int out_size, void* d_ws, size_t ws_size,
                              hipStream_t stream) {
    const float* xin = (const float*)d_in[0];
    const float* Wy0 = (const float*)d_in[1];
    const float* by0 = (const float*)d_in[2];
    const float* Wy1 = (const float*)d_in[3];
    const float* by1 = (const float*)d_in[4];
    const float* Wz1 = (const float*)d_in[5];
    const float* Wy2 = (const float*)d_in[6];
    const float* by2 = (const float*)d_in[7];
    const float* Wz2 = (const float*)d_in[8];
    float* out = (float*)d_out;

    blnn_kernel<<<dim3(NB / 4), dim3(256), 0, stream>>>(
        xin, Wy0, by0, Wy1, by1, Wz1, Wy2, by2, Wz2, out);
}